// Round 9
// baseline (229.659 us; speedup 1.0000x reference)
//
#include <hip/hip_runtime.h>
#include <cstdint>

#define BATCH 8
#define LQ 512
#define LK 2048
#define NH 16
#define DIM 64
#define HID 1024
#define NTOK (BATCH * LQ)   // 4096 tokens
#define NKT (LK / 64)       // 32 key tiles
#define KP 72               // pad: 144B row stride, 16B-aligned (R5 lesson: pad % 8 == 0!)
#define SC 0.1803368801111204f    // 0.125 * log2(e): folded into Q at pack time
#define NEGM (-1.4426950408889634e8f)  // -1e8 * log2(e): key-mask in exp2 domain

typedef _Float16 f16x8 __attribute__((ext_vector_type(8)));
typedef __fp16 half2v __attribute__((ext_vector_type(2)));
typedef float f32x4 __attribute__((ext_vector_type(4)));

#define MFMA(a, b, c) __builtin_amdgcn_mfma_f32_16x16x32_f16((a), (b), (c), 0, 0, 0)

__device__ __forceinline__ f16x8 ld8(const _Float16* p) { return *(const f16x8*)p; }

// async global->LDS, 16B per lane; lds dst is wave-uniform base (HW adds lane*16)
__device__ __forceinline__ void gl_lds16(const void* g, void* l) {
  __builtin_amdgcn_global_load_lds(
      (const __attribute__((address_space(1))) uint32_t*)g,
      (__attribute__((address_space(3))) uint32_t*)l, 16, 0, 0);
}

// LDS flush + barrier that does NOT drain vmcnt: in-flight global->VGPR
// loads survive (HK/m194 idiom).
__device__ __forceinline__ void lds_barrier() {
  asm volatile("s_waitcnt lgkmcnt(0)" ::: "memory");
  __builtin_amdgcn_s_barrier();
}

// 8 consecutive fp32 -> fp16 fragment (RTE scalar casts)
__device__ __forceinline__ f16x8 cvt8(const float* p) {
  const float4 a = *(const float4*)p;
  const float4 b = *(const float4*)(p + 4);
  f16x8 v;
  v[0] = (_Float16)a.x; v[1] = (_Float16)a.y; v[2] = (_Float16)a.z; v[3] = (_Float16)a.w;
  v[4] = (_Float16)b.x; v[5] = (_Float16)b.y; v[6] = (_Float16)b.z; v[7] = (_Float16)b.w;
  return v;
}

// pack 4 fp32 -> 4 fp16 (2x v_cvt_pkrtz) for ds_write_b64
__device__ __forceinline__ uint2 pk4(float a, float b, float c, float d) {
  union { half2v h2[2]; uint2 u; } t;
  t.h2[0] = __builtin_amdgcn_cvt_pkrtz(a, b);
  t.h2[1] = __builtin_amdgcn_cvt_pkrtz(c, d);
  return t.u;
}

// two float4 -> f16x8 via pkrtz
__device__ __forceinline__ f16x8 pk8(float4 a, float4 b) {
  union { half2v h2[4]; f16x8 v; } t;
  t.h2[0] = __builtin_amdgcn_cvt_pkrtz(a.x, a.y);
  t.h2[1] = __builtin_amdgcn_cvt_pkrtz(a.z, a.w);
  t.h2[2] = __builtin_amdgcn_cvt_pkrtz(b.x, b.y);
  t.h2[3] = __builtin_amdgcn_cvt_pkrtz(b.z, b.w);
  return t.v;
}

// ---------------------------------------------------------------------------
// Fully fused attention: Q/K/V projections + flash attention in one kernel.
// ROUND 9 = R8 TILE PIPELINE (77.2us, session best) + SPLIT-K OVER KEYS.
// Session audit: the "2 decoupled blocks/CU" config was NEVER tested --
// R3/R4 had grid 512 but LDS 65-66KB (>64KB -> 1 WG/CU per m93/m132's
// "64KB -> 2-3 blocks/CU" boundary); R6 had 62KB but grid 256 = 1/CU by
// construction. This kernel: blockIdx.z in {0,NZ) processes LK/NZ keys ->
// grid (128,2,2) = 512 blocks; Pl shrunk to one per-wave buffer (qt
// round-trips serialize) -> LDS 54KB <= 64KB; VGPR ~88 (5 waves/SIMD capacity
// -> 2 blocks x 2 waves fits). Disjoint key halves: no extra X reads.
// NZ==2 epilogue stores raw O partials (f32) + l partials; combine_kernel
// normalizes. NZ==1 path == R8 behavior (ws_size fallback).
// Per-tile structure unchanged: wave-specialized projections (waves 0-3: K,
// 4-7: V), reg-staged X, double-buffered Kl/Vl, mask via S-MFMA C-init,
// ONE lgkm-only barrier per tile, setprio on MFMA clusters, KP=72.
// ---------------------------------------------------------------------------
template <int NZ>
__global__ __launch_bounds__(512, 2) void attn_kernel(
    const float* __restrict__ Xq, const float* __restrict__ Xk,
    const float* __restrict__ Wq, const float* __restrict__ Wk,
    const float* __restrict__ Wv, const float* __restrict__ kg_mask,
    _Float16* __restrict__ ctx, float* __restrict__ Opart,
    float* __restrict__ lpart) {
  __shared__ __align__(16) _Float16 Kl[2][64 * KP];  // 18 KB: [key][e]
  __shared__ __align__(16) _Float16 Vl[2][64 * KP];  // 18 KB: [d][key]
  __shared__ __align__(16) _Float16 Pl[8][16 * KP];  // 18 KB: per-wave Q/P transpose
  const int tid = threadIdx.x;
  const int wave = tid >> 6, lane = tid & 63, l16 = lane & 15, quad = lane >> 4;
  const int kw = wave & 3;  // row-group for X/K/V projection work
  const int b = blockIdx.x >> 4, h = blockIdx.x & 15;
  const int qbase = blockIdx.y * 256;
  const int kz = blockIdx.z * (LK / NZ);  // this block's key-range base
  const int NT = NKT / NZ;                // tiles in this block's range
  const float* Xg = Xk + (size_t)b * LK * HID + h * 64;  // key-side X, this head's cols
  const float* mg = kg_mask + (size_t)b * LK;

  // X register staging: lane (quad,l16) of wave kw holds row kw*16+l16,
  // logical chunks 2q,2q+1 (floats 8q..8q+7) and 2q+8,2q+9 (8q+32..8q+39).
  const float* xrow0 = Xg + (size_t)(kw * 16 + l16) * HID + quad * 8;
  float4 xf0, xf1, xf2, xf3;
  auto loadX = [&](int kt) {  // kt = absolute key index
    const float* xr = xrow0 + (size_t)kt * HID;
    xf0 = *(const float4*)(xr);
    xf1 = *(const float4*)(xr + 4);
    xf2 = *(const float4*)(xr + 32);
    xf3 = *(const float4*)(xr + 36);
  };
  loadX(kz);  // in flight across the whole prologue

  // ---- fused Q projection: D[d_out][q] = Wq . Xq^T, scaled by SC ----
  f16x8 aq0[2], aq1[2];
  {
    f16x8 wq0[4], wq1[4];
#pragma unroll
    for (int nt = 0; nt < 4; ++nt) {
      const float* wp = Wq + (nt * 16 + l16) * DIM + quad * 8;
      wq0[nt] = cvt8(wp);
      wq1[nt] = cvt8(wp + 32);
    }
#pragma unroll
    for (int qt = 0; qt < 2; ++qt) {
      const int qg = qbase + wave * 32 + qt * 16 + l16;
      const float* xpq = Xq + (size_t)(b * LQ + qg) * HID + h * 64 + quad * 8;
      const f16x8 bq0 = cvt8(xpq), bq1 = cvt8(xpq + 32);
#pragma unroll
      for (int nt = 0; nt < 4; ++nt) {
        f32x4 d = {0.f, 0.f, 0.f, 0.f};
        d = MFMA(wq0[nt], bq0, d);
        d = MFMA(wq1[nt], bq1, d);
        *(uint2*)&Pl[wave][l16 * KP + nt * 16 + quad * 4] =
            pk4(d[0] * SC, d[1] * SC, d[2] * SC, d[3] * SC);
      }
      aq0[qt] = ld8(&Pl[wave][l16 * KP + quad * 8]);
      aq1[qt] = ld8(&Pl[wave][l16 * KP + 32 + quad * 8]);
    }
  }

  // ---- projection weight fragments, once per block: waves 0-3 hold Wk
  // (A-operand of K proj), waves 4-7 hold Wv (B-operand of V proj). ----
  const float* Wsel = (wave < 4) ? Wk : Wv;
  f16x8 aw0[4], aw1[4];
#pragma unroll
  for (int nt = 0; nt < 4; ++nt) {
    const float* wp = Wsel + (nt * 16 + l16) * DIM + quad * 8;
    aw0[nt] = cvt8(wp);
    aw1[nt] = cvt8(wp + 32);
  }

  const f32x4 z4 = {0.f, 0.f, 0.f, 0.f};

  // ---- proj(0) into buffer 0 (xf holds X[kz]; compiler waits vmcnt here) ----
  {
    const f16x8 bx0 = pk8(xf0, xf1), bx1 = pk8(xf2, xf3);
    if (wave < 4) {
#pragma unroll
      for (int nt = 0; nt < 4; ++nt) {
        f32x4 d = z4;
        d = MFMA(aw0[nt], bx0, d);
        d = MFMA(aw1[nt], bx1, d);
        *(uint2*)&Kl[0][(kw * 16 + l16) * KP + nt * 16 + quad * 4] =
            pk4(d[0], d[1], d[2], d[3]);
      }
    } else {
#pragma unroll
      for (int dt = 0; dt < 4; ++dt) {
        f32x4 d = z4;
        d = MFMA(bx0, aw0[dt], d);
        d = MFMA(bx1, aw1[dt], d);
        *(uint2*)&Vl[0][(dt * 16 + l16) * KP + kw * 16 + quad * 4] =
            pk4(d[0], d[1], d[2], d[3]);
      }
    }
  }
  loadX(kz + 64); // X[1] in flight across the barrier
  lds_barrier();  // publishes KV[0]; X loads NOT drained

  f32x4 o[2][4];
  float l_run[2] = {0.f, 0.f};
#pragma unroll
  for (int qt = 0; qt < 2; ++qt)
#pragma unroll
    for (int i = 0; i < 4; ++i) o[qt][i] = z4;

  for (int t = 0; t < NT; ++t) {
    const int buf = t & 1;
    const int kt = kz + t * 64;

    // mask loads first (vmem FIFO: older X[t+1] loads drain independently;
    // waiting on these later leaves X[t+2] in flight). L2-hot, quad-broadcast.
    float4 mq[4];
#pragma unroll
    for (int nt = 0; nt < 4; ++nt)
      mq[nt] = *(const float4*)(mg + kt + nt * 16 + quad * 4);

    // ---- proj(t+1) into buf^1 (reads nothing of buf; races nothing) ----
    if (t + 1 < NT) {
      const f16x8 bx0 = pk8(xf0, xf1), bx1 = pk8(xf2, xf3);  // counted vmcnt wait
      if (wave < 4) {
#pragma unroll
        for (int nt = 0; nt < 4; ++nt) {
          f32x4 d = z4;
          d = MFMA(aw0[nt], bx0, d);
          d = MFMA(aw1[nt], bx1, d);
          *(uint2*)&Kl[buf ^ 1][(kw * 16 + l16) * KP + nt * 16 + quad * 4] =
              pk4(d[0], d[1], d[2], d[3]);
        }
      } else {
#pragma unroll
        for (int dt = 0; dt < 4; ++dt) {
          f32x4 d = z4;
          d = MFMA(bx0, aw0[dt], d);
          d = MFMA(bx1, aw1[dt], d);
          *(uint2*)&Vl[buf ^ 1][(dt * 16 + l16) * KP + kw * 16 + quad * 4] =
              pk4(d[0], d[1], d[2], d[3]);
        }
      }
      if (t + 2 < NT) loadX(kt + 128);  // X[t+2]: in flight across next barrier
    }

    // additive mask in exp2 domain, as S-accumulator INIT (D-layout match:
    // C[r] = mask[key=nt*16+quad*4+r]); fma form: NEGM - m*NEGM
    f32x4 cin[4];
#pragma unroll
    for (int nt = 0; nt < 4; ++nt) {
      cin[nt][0] = __builtin_fmaf(mq[nt].x, -NEGM, NEGM);
      cin[nt][1] = __builtin_fmaf(mq[nt].y, -NEGM, NEGM);
      cin[nt][2] = __builtin_fmaf(mq[nt].z, -NEGM, NEGM);
      cin[nt][3] = __builtin_fmaf(mq[nt].w, -NEGM, NEGM);
    }

    // S^T = K.Q^T : D[key=nt*16+quad*4+r][q=l16], C-init = mask; P = exp2(S)
    float p[2][4][4];
    __builtin_amdgcn_s_setprio(1);
#pragma unroll
    for (int nt = 0; nt < 4; ++nt) {
      const f16x8 kb0 = ld8(&Kl[buf][(nt * 16 + l16) * KP + quad * 8]);
      const f16x8 kb1 = ld8(&Kl[buf][(nt * 16 + l16) * KP + 32 + quad * 8]);
#pragma unroll
      for (int qt = 0; qt < 2; ++qt) {
        f32x4 s = cin[nt];
        s = MFMA(kb0, aq0[qt], s);
        s = MFMA(kb1, aq1[qt], s);
        const float e0 = __builtin_amdgcn_exp2f(s[0]);
        const float e1 = __builtin_amdgcn_exp2f(s[1]);
        const float e2 = __builtin_amdgcn_exp2f(s[2]);
        const float e3 = __builtin_amdgcn_exp2f(s[3]);
        l_run[qt] += (e0 + e1) + (e2 + e3);
        p[qt][nt][0] = e0; p[qt][nt][1] = e1; p[qt][nt][2] = e2; p[qt][nt][3] = e3;
      }
    }
    __builtin_amdgcn_s_setprio(0);

    // P: C-layout -> A-layout via the per-wave LDS buffer, qt serialized
    // (single buffer keeps total LDS at 54KB <= 64KB for 2 blocks/CU).
    f16x8 ap0[2], ap1[2];
#pragma unroll
    for (int qt = 0; qt < 2; ++qt) {
#pragma unroll
      for (int nt = 0; nt < 4; ++nt)
        *(uint2*)&Pl[wave][l16 * KP + nt * 16 + quad * 4] =
            pk4(p[qt][nt][0], p[qt][nt][1], p[qt][nt][2], p[qt][nt][3]);
      ap0[qt] = ld8(&Pl[wave][l16 * KP + quad * 8]);
      ap1[qt] = ld8(&Pl[wave][l16 * KP + 32 + quad * 8]);
    }

    // O^T += V.P^T : D[d=dt*16+quad*4+r][q=l16]
    __builtin_amdgcn_s_setprio(1);
#pragma unroll
    for (int dt = 0; dt < 4; ++dt) {
      const f16x8 vb0 = ld8(&Vl[buf][(dt * 16 + l16) * KP + quad * 8]);
      const f16x8 vb1 = ld8(&Vl[buf][(dt * 16 + l16) * KP + 32 + quad * 8]);
#pragma unroll
      for (int qt = 0; qt < 2; ++qt) {
        o[qt][dt] = MFMA(vb0, ap0[qt], o[qt][dt]);
        o[qt][dt] = MFMA(vb1, ap1[qt], o[qt][dt]);
      }
    }
    __builtin_amdgcn_s_setprio(0);

    lds_barrier();  // publishes KV[t+1]; guards buf reuse; X loads survive
  }

  // row-sum: lane covers its quad's 16 keys; finish across quads
#pragma unroll
  for (int qt = 0; qt < 2; ++qt) {
    float s = l_run[qt];
    s += __shfl_xor(s, 16);
    s += __shfl_xor(s, 32);
    const int qg = qbase + wave * 32 + qt * 16 + l16;
    if constexpr (NZ == 1) {
      // direct ctx write (token, h*64+d): packed 8B stores
      const float inv = 1.f / s;
      _Float16* base = ctx + (size_t)(b * LQ + qg) * HID + h * 64;
#pragma unroll
      for (int dt = 0; dt < 4; ++dt)
        *(uint2*)(base + dt * 16 + quad * 4) =
            pk4(o[qt][dt][0] * inv, o[qt][dt][1] * inv,
                o[qt][dt][2] * inv, o[qt][dt][3] * inv);
    } else {
      // partial: raw O (f32) + l; combine_kernel normalizes
      if (quad == 0)
        lpart[((size_t)(blockIdx.z * BATCH + b) * NH + h) * LQ + qg] = s;
      float* obase = Opart + (size_t)blockIdx.z * NTOK * HID +
                     (size_t)(b * LQ + qg) * HID + h * 64;
#pragma unroll
      for (int dt = 0; dt < 4; ++dt) {
        float4 ov;
        ov.x = o[qt][dt][0]; ov.y = o[qt][dt][1];
        ov.z = o[qt][dt][2]; ov.w = o[qt][dt][3];
        *(float4*)(obase + dt * 16 + quad * 4) = ov;
      }
    }
  }
}

// ---------------------------------------------------------------------------
// Split-K combine: ctx = (O0 + O1) / (l0 + l1), fp16 pack. One block/token.
// ~40MB traffic, memory-bound, ~7us.
// ---------------------------------------------------------------------------
__global__ __launch_bounds__(256) void combine_kernel(
    const float* __restrict__ Opart, const float* __restrict__ lpart,
    _Float16* __restrict__ ctx) {
  const int tok = blockIdx.x, t = threadIdx.x;
  const int b = tok >> 9, q = tok & 511;
  const int hh = t >> 4;  // head = (4t)/64
  const float l0 = lpart[((size_t)b * NH + hh) * LQ + q];
  const float l1 = lpart[((size_t)(BATCH + b) * NH + hh) * LQ + q];
  const float inv = 1.f / (l0 + l1);
  const size_t off = (size_t)tok * HID + t * 4;
  const float4 a = *(const float4*)(Opart + off);
  const float4 c = *(const float4*)(Opart + (size_t)NTOK * HID + off);
  *(uint2*)(ctx + off) = pk4((a.x + c.x) * inv, (a.y + c.y) * inv,
                             (a.z + c.z) * inv, (a.w + c.w) * inv);
}

// ---------------------------------------------------------------------------
// W_lin fp32 -> fp16 (once; 2MB result stays L2-resident for linear_kernel)
// ---------------------------------------------------------------------------
__global__ __launch_bounds__(256) void wconv_kernel(const float* __restrict__ W,
                                                    _Float16* __restrict__ Wh) {
  const int i = blockIdx.x * 256 + threadIdx.x;
  const float4 v = ((const float4*)W)[i];
  ((uint2*)Wh)[i] = pk4(v.x, v.y, v.z, v.w);
}

// ---------------------------------------------------------------------------
// lin = ctx @ Wh^T + b; X = erf-GELU(lin) + resid. 128x128 tile, 512 threads
// (8 waves as 2x4), BK=64, double-buffered global_load_lds, 1 barrier/chunk.
// ---------------------------------------------------------------------------
__global__ __launch_bounds__(512) void linear_kernel(const _Float16* __restrict__ A,
                                                     const _Float16* __restrict__ Wh,
                                                     const float* __restrict__ bias,
                                                     const float* __restrict__ resid,
                                                     float* __restrict__ Xout) {
  __shared__ __align__(16) _Float16 Al[2][128 * 64];
  __shared__ __align__(16) _Float16 Bl[2][128 * 64];
  const int tid = threadIdx.x;
  const int wave = tid >> 6, lane = tid & 63, l16 = lane & 15, quad = lane >> 4;
  const int wm = wave >> 2, wn = wave & 3;
  const int nbase = blockIdx.x * 128, mbase = blockIdx.y * 128;
  const int srow = wave * 16 + (lane >> 3);
  const int sc = lane & 7;

  auto stage = [&](int kk, int nbuf) {
#pragma unroll
    for (int i = 0; i < 2; ++i) {
      const int row = srow + i * 8;
      const int c = sc ^ (row & 7);
      gl_lds16(A + (size_t)(mbase + row) * HID + kk + c * 8,
               &Al[nbuf][(wave * 16 + i * 8) * 64]);
      gl_lds16(Wh + (size_t)(nbase + row) * HID + kk + c * 8,
               &Bl[nbuf][(wave * 16 + i * 8) * 64]);
    }
  };

  const f32x4 z4 = {0.f, 0.f, 0.f, 0.f};
  f32x4 acc[4][2];
#pragma unroll
  for (int mt = 0; mt < 4; ++mt)
#pragma unroll
    for (int nt = 0; nt < 2; ++nt) acc[mt][nt] = z4;

  stage(0, 0);
  for (int t = 0; t < HID / 64; ++t) {
    const int buf = t & 1;
    __syncthreads();
    if (t + 1 < HID / 64) stage((t + 1) * 64, buf ^ 1);
    const int sw = l16 & 7;
    f16x8 b0[2], b1[2];
#pragma unroll
    for (int nt = 0; nt < 2; ++nt) {
      const int brow = wn * 32 + nt * 16 + l16;
      b0[nt] = ld8(&Bl[buf][brow * 64 + (quad ^ sw) * 8]);
      b1[nt] = ld8(&Bl[buf][brow * 64 + ((quad + 4) ^ sw) * 8]);
    }
#pragma unroll
    for (int mt = 0; mt < 4; ++mt) {
      const int arow = wm * 64 + mt * 16 + l16;
      const f16x8 a0 = ld8(&Al[buf][arow * 64 + (quad ^ sw) * 8]);
      const f16x8 a1 = ld8(&Al[buf][arow * 64 + ((quad + 4) ^ sw) * 8]);
#pragma unroll
      for (int nt = 0; nt < 2; ++nt) {
        acc[mt][nt] = MFMA(a0, b0[nt], acc[mt][nt]);
        acc[mt][nt] = MFMA(a1, b1[nt], acc[mt][nt]);
      }
    }
  }
#pragma unroll
  for (int nt = 0; nt < 2; ++nt) {
    const int col = nbase + wn * 32 + nt * 16 + l16;
    const float bv = bias[col];
#pragma unroll
    for (int mt = 0; mt < 4; ++mt) {
#pragma unroll
      for (int r = 0; r < 4; ++r) {
        const int row = mbase + wm * 64 + mt * 16 + quad * 4 + r;
        const float v = acc[mt][nt][r] + bv;
        const float g = 0.5f * v * (1.f + erff(v * 0.70710678118654752f));
        Xout[(size_t)row * HID + col] = g + resid[(size_t)row * HID + col];
      }
    }
  }
}

// ---------------------------------------------------------------------------
// LayerNorm over HID=1024 per token row.
// ---------------------------------------------------------------------------
__global__ __launch_bounds__(256) void ln_kernel(const float* __restrict__ X,
                                                 const float* __restrict__ gamma,
                                                 const float* __restrict__ beta,
                                                 float* __restrict__ out) {
  const int row = blockIdx.x, tid = threadIdx.x;
  const int lane = tid & 63, wave = tid >> 6;
  const float4 v = *(const float4*)(X + (size_t)row * HID + tid * 4);
  float s1 = v.x + v.y + v.z + v.w;
  float s2 = v.x * v.x + v.y * v.y + v.z * v.z + v.w * v.w;
#pragma unroll
  for (int off = 1; off < 64; off <<= 1) {
    s1 += __shfl_xor(s1, off);
    s2 += __shfl_xor(s2, off);
  }
  __shared__ float r1[4], r2[4];
  if (lane == 0) { r1[wave] = s1; r2[wave] = s2; }
  __syncthreads();
  s1 = r1[0] + r1[1] + r1[2] + r1[3];
  s2 = r2[0] + r2[1] + r2[2] + r2[3];
  const float mu = s1 * (1.f / HID);
  const float var = s2 * (1.f / HID) - mu * mu;
  const float rstd = rsqrtf(var + 1e-5f);
  const float4 g = *(const float4*)(gamma + tid * 4);
  const float4 be = *(const float4*)(beta + tid * 4);
  float4 ov;
  ov.x = (v.x - mu) * rstd * g.x + be.x;
  ov.y = (v.y - mu) * rstd * g.y + be.y;
  ov.z = (v.z - mu) * rstd * g.z + be.z;
  ov.w = (v.w - mu) * rstd * g.w + be.w;
  *(float4*)(out + (size_t)row * HID + tid * 4) = ov;
}

// ---------------------------------------------------------------------------
// Workspace:
//   ctx   fp16 [ 0,  8M)
//   Xb    fp32 [ 8M, 24M)
//   Wh    fp16 [24M, 26M)
//   Opart fp32 [26M, 58M)   (split-K only)
//   lpart fp32 [58M, 58.5M) (split-K only)
// ---------------------------------------------------------------------------
extern "C" void kernel_launch(void* const* d_in, const int* in_sizes, int n_in,
                              void* d_out, int out_size, void* d_ws, size_t ws_size,
                              hipStream_t stream) {
  (void)in_sizes; (void)n_in; (void)out_size;
  const float* input_embed = (const float*)d_in[0];
  const float* kg_embed    = (const float*)d_in[1];
  // d_in[2] = input_mask: additive per-query constant -> softmax-invariant, unused
  const float* kg_mask = (const float*)d_in[3];
  const float* Wq    = (const float*)d_in[4];
  const float* Wk    = (const float*)d_in[5];
  const float* Wv    = (const float*)d_in[6];
  const float* W_lin = (const float*)d_in[7];
  const float* b_lin = (const float*)d_in[8];
  const float* gamma = (const float*)d_in[9];
  const float* beta  = (const float*)d_in[10];

  char* ws = (char*)d_ws;
  _Float16* ctx = (_Float16*)(ws);
  float*    Xb  = (float*)(ws + (8u << 20));
  _Float16* Wh  = (_Float16*)(ws + (24u << 20));
  float* Opart  = (float*)(ws + (26u << 20));
  float* lpart  = (float*)(ws + (58u << 20));

  if (ws_size >= (59ull << 20)) {
    attn_kernel<2><<<dim3(128, 2, 2), dim3(512), 0, stream>>>(
        input_embed, kg_embed, Wq, Wk, Wv, kg_mask, ctx, Opart, lpart);
    combine_kernel<<<dim3(NTOK), dim3(256), 0, stream>>>(Opart, lpart, ctx);
  } else {
    attn_kernel<1><<<dim3(128, 2, 1), dim3(512), 0, stream>>>(
        input_embed, kg_embed, Wq, Wk, Wv, kg_mask, ctx, Opart, lpart);
  }
  wconv_kernel<<<dim3(1024), dim3(256), 0, stream>>>(W_lin, Wh);
  linear_kernel<<<dim3(8, 32), dim3(512), 0, stream>>>(ctx, Wh, b_lin, input_embed, Xb);
  ln_kernel<<<dim3(NTOK), dim3(256), 0, stream>>>(Xb, gamma, beta, (float*)d_out);
}

// Round 10
// 214.002 us; speedup vs baseline: 1.0732x; 1.0732x over previous
//
#include <hip/hip_runtime.h>
#include <cstdint>

#define BATCH 8
#define LQ 512
#define LK 2048
#define NH 16
#define DIM 64
#define HID 1024
#define NTOK (BATCH * LQ)   // 4096 tokens
#define NKT (LK / 64)       // 32 key tiles
#define KP 72               // pad: 144B row stride, 16B-aligned (R5 lesson: pad % 8 == 0!)
#define SC 0.1803368801111204f    // 0.125 * log2(e): folded into Q at pack time
#define NEGM (-1.4426950408889634e8f)  // -1e8 * log2(e): key-mask in exp2 domain

typedef _Float16 f16x8 __attribute__((ext_vector_type(8)));
typedef __fp16 half2v __attribute__((ext_vector_type(2)));
typedef float f32x4 __attribute__((ext_vector_type(4)));

#define MFMA(a, b, c) __builtin_amdgcn_mfma_f32_16x16x32_f16((a), (b), (c), 0, 0, 0)

__device__ __forceinline__ f16x8 ld8(const _Float16* p) { return *(const f16x8*)p; }

// async global->LDS, 16B per lane; lds dst is wave-uniform base (HW adds lane*16)
__device__ __forceinline__ void gl_lds16(const void* g, void* l) {
  __builtin_amdgcn_global_load_lds(
      (const __attribute__((address_space(1))) uint32_t*)g,
      (__attribute__((address_space(3))) uint32_t*)l, 16, 0, 0);
}

// LDS flush + barrier that does NOT drain vmcnt: in-flight global->VGPR
// loads survive (HK/m194 idiom).
__device__ __forceinline__ void lds_barrier() {
  asm volatile("s_waitcnt lgkmcnt(0)" ::: "memory");
  __builtin_amdgcn_s_barrier();
}

// 8 consecutive fp32 -> fp16 fragment (RTE scalar casts)
__device__ __forceinline__ f16x8 cvt8(const float* p) {
  const float4 a = *(const float4*)p;
  const float4 b = *(const float4*)(p + 4);
  f16x8 v;
  v[0] = (_Float16)a.x; v[1] = (_Float16)a.y; v[2] = (_Float16)a.z; v[3] = (_Float16)a.w;
  v[4] = (_Float16)b.x; v[5] = (_Float16)b.y; v[6] = (_Float16)b.z; v[7] = (_Float16)b.w;
  return v;
}

// pack 4 fp32 -> 4 fp16 (2x v_cvt_pkrtz) for ds_write_b64
__device__ __forceinline__ uint2 pk4(float a, float b, float c, float d) {
  union { half2v h2[2]; uint2 u; } t;
  t.h2[0] = __builtin_amdgcn_cvt_pkrtz(a, b);
  t.h2[1] = __builtin_amdgcn_cvt_pkrtz(c, d);
  return t.u;
}

// two float4 -> f16x8 via pkrtz
__device__ __forceinline__ f16x8 pk8(float4 a, float4 b) {
  union { half2v h2[4]; f16x8 v; } t;
  t.h2[0] = __builtin_amdgcn_cvt_pkrtz(a.x, a.y);
  t.h2[1] = __builtin_amdgcn_cvt_pkrtz(a.z, a.w);
  t.h2[2] = __builtin_amdgcn_cvt_pkrtz(b.x, b.y);
  t.h2[3] = __builtin_amdgcn_cvt_pkrtz(b.z, b.w);
  return t.v;
}

// ---------------------------------------------------------------------------
// Fully fused attention: Q/K/V projections + flash attention in one kernel.
// ROUND 10 = R8 (210.65us best; attn 77.2) + EARLY V-FRAGMENT LOADS.
// R9 lesson: 2-WG/CU co-residency does not materialize on this machine at
// ANY LDS size (54KB, 512 blocks -> occupancy still 20%, wall-clock = two
// sequential rounds); split-K costs 13us attn + 7us combine -> reverted.
// This round, scheduling-only: the 8 ds_read_b128 V-fragment loads moved
// from after the P round-trip to the TOP of the compute phase. They depend
// only on Vl[buf] (published at the last barrier); their latency hides under
// the S-MFMAs + exp2, and lgkm FIFO order means the (later) P reads retiring
// implies V is in registers -> O-MFMAs start immediately after P. +32 live
// VGPR during S (~88 -> ~115-125): free, since 1 block x 8 waves = 2
// waves/SIMD which persists to 256 VGPR. Spill tripwire: WRITE_SIZE.
// Per (b,h) x 256-q block: grid (128,2), 512 thr / 8 waves. Wave-specialized
// projections (waves 0-3: K, 4-7: V), reg-staged X, double-buffered Kl/Vl,
// mask via S-MFMA C-init, ONE lgkm-only barrier/tile, setprio, KP=72.
// ---------------------------------------------------------------------------
__global__ __launch_bounds__(512, 2) void attn_kernel(
    const float* __restrict__ Xq, const float* __restrict__ Xk,
    const float* __restrict__ Wq, const float* __restrict__ Wk,
    const float* __restrict__ Wv, const float* __restrict__ kg_mask,
    _Float16* __restrict__ ctx) {
  __shared__ __align__(16) _Float16 Kl[2][64 * KP];    // 18 KB: [key][e]
  __shared__ __align__(16) _Float16 Vl[2][64 * KP];    // 18 KB: [d][key]
  __shared__ __align__(16) _Float16 Pl[8][2][16 * KP]; // 36 KB: per-wave/qt P transpose
  const int tid = threadIdx.x;
  const int wave = tid >> 6, lane = tid & 63, l16 = lane & 15, quad = lane >> 4;
  const int kw = wave & 3;  // row-group for X/K/V projection work
  const int b = blockIdx.x >> 4, h = blockIdx.x & 15;
  const int qbase = blockIdx.y * 256;
  const float* Xg = Xk + (size_t)b * LK * HID + h * 64;  // key-side X, this head's cols
  const float* mg = kg_mask + (size_t)b * LK;

  // X register staging: lane (quad,l16) of wave kw holds row kw*16+l16,
  // logical chunks 2q,2q+1 (floats 8q..8q+7) and 2q+8,2q+9 (8q+32..8q+39).
  const float* xrow0 = Xg + (size_t)(kw * 16 + l16) * HID + quad * 8;
  float4 xf0, xf1, xf2, xf3;
  auto loadX = [&](int kt) {
    const float* xr = xrow0 + (size_t)kt * HID;
    xf0 = *(const float4*)(xr);
    xf1 = *(const float4*)(xr + 4);
    xf2 = *(const float4*)(xr + 32);
    xf3 = *(const float4*)(xr + 36);
  };
  loadX(0);  // in flight across the whole prologue

  // ---- fused Q projection: D[d_out][q] = Wq . Xq^T, scaled by SC ----
  f16x8 aq0[2], aq1[2];
  {
    f16x8 wq0[4], wq1[4];
#pragma unroll
    for (int nt = 0; nt < 4; ++nt) {
      const float* wp = Wq + (nt * 16 + l16) * DIM + quad * 8;
      wq0[nt] = cvt8(wp);
      wq1[nt] = cvt8(wp + 32);
    }
#pragma unroll
    for (int qt = 0; qt < 2; ++qt) {
      const int qg = qbase + wave * 32 + qt * 16 + l16;
      const float* xpq = Xq + (size_t)(b * LQ + qg) * HID + h * 64 + quad * 8;
      const f16x8 bq0 = cvt8(xpq), bq1 = cvt8(xpq + 32);
#pragma unroll
      for (int nt = 0; nt < 4; ++nt) {
        f32x4 d = {0.f, 0.f, 0.f, 0.f};
        d = MFMA(wq0[nt], bq0, d);
        d = MFMA(wq1[nt], bq1, d);
        *(uint2*)&Pl[wave][qt][l16 * KP + nt * 16 + quad * 4] =
            pk4(d[0] * SC, d[1] * SC, d[2] * SC, d[3] * SC);
      }
      aq0[qt] = ld8(&Pl[wave][qt][l16 * KP + quad * 8]);
      aq1[qt] = ld8(&Pl[wave][qt][l16 * KP + 32 + quad * 8]);
    }
  }

  // ---- projection weight fragments, once per block: waves 0-3 hold Wk
  // (A-operand of K proj), waves 4-7 hold Wv (B-operand of V proj). ----
  const float* Wsel = (wave < 4) ? Wk : Wv;
  f16x8 aw0[4], aw1[4];
#pragma unroll
  for (int nt = 0; nt < 4; ++nt) {
    const float* wp = Wsel + (nt * 16 + l16) * DIM + quad * 8;
    aw0[nt] = cvt8(wp);
    aw1[nt] = cvt8(wp + 32);
  }

  const f32x4 z4 = {0.f, 0.f, 0.f, 0.f};

  // ---- proj(0) into buffer 0 (xf holds X[0]; compiler waits vmcnt here) ----
  {
    const f16x8 bx0 = pk8(xf0, xf1), bx1 = pk8(xf2, xf3);
    if (wave < 4) {
#pragma unroll
      for (int nt = 0; nt < 4; ++nt) {
        f32x4 d = z4;
        d = MFMA(aw0[nt], bx0, d);
        d = MFMA(aw1[nt], bx1, d);
        *(uint2*)&Kl[0][(kw * 16 + l16) * KP + nt * 16 + quad * 4] =
            pk4(d[0], d[1], d[2], d[3]);
      }
    } else {
#pragma unroll
      for (int dt = 0; dt < 4; ++dt) {
        f32x4 d = z4;
        d = MFMA(bx0, aw0[dt], d);
        d = MFMA(bx1, aw1[dt], d);
        *(uint2*)&Vl[0][(dt * 16 + l16) * KP + kw * 16 + quad * 4] =
            pk4(d[0], d[1], d[2], d[3]);
      }
    }
  }
  loadX(64);      // X[1] in flight across the barrier
  lds_barrier();  // publishes KV[0]; X loads NOT drained

  f32x4 o[2][4];
  float l_run[2] = {0.f, 0.f};
#pragma unroll
  for (int qt = 0; qt < 2; ++qt)
#pragma unroll
    for (int i = 0; i < 4; ++i) o[qt][i] = z4;

  for (int t = 0; t < NKT; ++t) {
    const int buf = t & 1;
    const int kt = t * 64;

    // mask loads first (vmem FIFO: older X[t+1] loads drain independently;
    // waiting on these later leaves X[t+2] in flight). L2-hot, quad-broadcast.
    float4 mq[4];
#pragma unroll
    for (int nt = 0; nt < 4; ++nt)
      mq[nt] = *(const float4*)(mg + kt + nt * 16 + quad * 4);

    // ---- proj(t+1) into buf^1 (reads nothing of buf; races nothing) ----
    if (t + 1 < NKT) {
      const f16x8 bx0 = pk8(xf0, xf1), bx1 = pk8(xf2, xf3);  // counted vmcnt wait
      if (wave < 4) {
#pragma unroll
        for (int nt = 0; nt < 4; ++nt) {
          f32x4 d = z4;
          d = MFMA(aw0[nt], bx0, d);
          d = MFMA(aw1[nt], bx1, d);
          *(uint2*)&Kl[buf ^ 1][(kw * 16 + l16) * KP + nt * 16 + quad * 4] =
              pk4(d[0], d[1], d[2], d[3]);
        }
      } else {
#pragma unroll
        for (int dt = 0; dt < 4; ++dt) {
          f32x4 d = z4;
          d = MFMA(bx0, aw0[dt], d);
          d = MFMA(bx1, aw1[dt], d);
          *(uint2*)&Vl[buf ^ 1][(dt * 16 + l16) * KP + kw * 16 + quad * 4] =
              pk4(d[0], d[1], d[2], d[3]);
        }
      }
      if (t + 2 < NKT) loadX(kt + 128);  // X[t+2]: in flight across next barrier
    }

    // EARLY V-fragment loads: depend only on Vl[buf] (published at last
    // barrier). Issued before the S phase so their latency hides under the
    // S-MFMAs + exp2; lgkm FIFO order means the later P reads retiring
    // implies these are complete. +32 live VGPR (free at 2 waves/SIMD).
    f16x8 vb0[4], vb1[4];
#pragma unroll
    for (int dt = 0; dt < 4; ++dt) {
      vb0[dt] = ld8(&Vl[buf][(dt * 16 + l16) * KP + quad * 8]);
      vb1[dt] = ld8(&Vl[buf][(dt * 16 + l16) * KP + 32 + quad * 8]);
    }

    // additive mask in exp2 domain, as S-accumulator INIT (D-layout match:
    // C[r] = mask[key=nt*16+quad*4+r]); fma form: NEGM - m*NEGM
    f32x4 cin[4];
#pragma unroll
    for (int nt = 0; nt < 4; ++nt) {
      cin[nt][0] = __builtin_fmaf(mq[nt].x, -NEGM, NEGM);
      cin[nt][1] = __builtin_fmaf(mq[nt].y, -NEGM, NEGM);
      cin[nt][2] = __builtin_fmaf(mq[nt].z, -NEGM, NEGM);
      cin[nt][3] = __builtin_fmaf(mq[nt].w, -NEGM, NEGM);
    }

    // S^T = K.Q^T : D[key=nt*16+quad*4+r][q=l16], C-init = mask; P = exp2(S)
    float p[2][4][4];
    __builtin_amdgcn_s_setprio(1);
#pragma unroll
    for (int nt = 0; nt < 4; ++nt) {
      const f16x8 kb0 = ld8(&Kl[buf][(nt * 16 + l16) * KP + quad * 8]);
      const f16x8 kb1 = ld8(&Kl[buf][(nt * 16 + l16) * KP + 32 + quad * 8]);
#pragma unroll
      for (int qt = 0; qt < 2; ++qt) {
        f32x4 s = cin[nt];
        s = MFMA(kb0, aq0[qt], s);
        s = MFMA(kb1, aq1[qt], s);
        const float e0 = __builtin_amdgcn_exp2f(s[0]);
        const float e1 = __builtin_amdgcn_exp2f(s[1]);
        const float e2 = __builtin_amdgcn_exp2f(s[2]);
        const float e3 = __builtin_amdgcn_exp2f(s[3]);
        l_run[qt] += (e0 + e1) + (e2 + e3);
        p[qt][nt][0] = e0; p[qt][nt][1] = e1; p[qt][nt][2] = e2; p[qt][nt][3] = e3;
      }
    }
    __builtin_amdgcn_s_setprio(0);

    // P: C-layout -> A-layout, per-wave per-qt buffers; write both qt then
    // read both so the two LDS round-trip latencies overlap
#pragma unroll
    for (int qt = 0; qt < 2; ++qt)
#pragma unroll
      for (int nt = 0; nt < 4; ++nt)
        *(uint2*)&Pl[wave][qt][l16 * KP + nt * 16 + quad * 4] =
            pk4(p[qt][nt][0], p[qt][nt][1], p[qt][nt][2], p[qt][nt][3]);
    f16x8 ap0[2], ap1[2];
#pragma unroll
    for (int qt = 0; qt < 2; ++qt) {
      ap0[qt] = ld8(&Pl[wave][qt][l16 * KP + quad * 8]);
      ap1[qt] = ld8(&Pl[wave][qt][l16 * KP + 32 + quad * 8]);
    }

    // O^T += V.P^T : D[d=dt*16+quad*4+r][q=l16] (V already in registers)
    __builtin_amdgcn_s_setprio(1);
#pragma unroll
    for (int dt = 0; dt < 4; ++dt) {
#pragma unroll
      for (int qt = 0; qt < 2; ++qt) {
        o[qt][dt] = MFMA(vb0[dt], ap0[qt], o[qt][dt]);
        o[qt][dt] = MFMA(vb1[dt], ap1[qt], o[qt][dt]);
      }
    }
    __builtin_amdgcn_s_setprio(0);

    lds_barrier();  // publishes KV[t+1]; guards buf reuse; X loads survive
  }

  // row-sum: lane covers its quad's 16 keys; finish across quads
  float inv[2];
#pragma unroll
  for (int qt = 0; qt < 2; ++qt) {
    float s = l_run[qt];
    s += __shfl_xor(s, 16);
    s += __shfl_xor(s, 32);
    inv[qt] = 1.f / s;
  }
  // ctx (token, h*64+d): lane's 4 d-values contiguous -> packed 8B stores
#pragma unroll
  for (int qt = 0; qt < 2; ++qt) {
    const int qg = qbase + wave * 32 + qt * 16 + l16;
    _Float16* base = ctx + (size_t)(b * LQ + qg) * HID + h * 64;
#pragma unroll
    for (int dt = 0; dt < 4; ++dt)
      *(uint2*)(base + dt * 16 + quad * 4) =
          pk4(o[qt][dt][0] * inv[qt], o[qt][dt][1] * inv[qt],
              o[qt][dt][2] * inv[qt], o[qt][dt][3] * inv[qt]);
  }
}

// ---------------------------------------------------------------------------
// W_lin fp32 -> fp16 (once; 2MB result stays L2-resident for linear_kernel)
// ---------------------------------------------------------------------------
__global__ __launch_bounds__(256) void wconv_kernel(const float* __restrict__ W,
                                                    _Float16* __restrict__ Wh) {
  const int i = blockIdx.x * 256 + threadIdx.x;
  const float4 v = ((const float4*)W)[i];
  ((uint2*)Wh)[i] = pk4(v.x, v.y, v.z, v.w);
}

// ---------------------------------------------------------------------------
// lin = ctx @ Wh^T + b; X = erf-GELU(lin) + resid. 128x128 tile, 512 threads
// (8 waves as 2x4), BK=64, double-buffered global_load_lds, 1 barrier/chunk.
// ---------------------------------------------------------------------------
__global__ __launch_bounds__(512) void linear_kernel(const _Float16* __restrict__ A,
                                                     const _Float16* __restrict__ Wh,
                                                     const float* __restrict__ bias,
                                                     const float* __restrict__ resid,
                                                     float* __restrict__ Xout) {
  __shared__ __align__(16) _Float16 Al[2][128 * 64];
  __shared__ __align__(16) _Float16 Bl[2][128 * 64];
  const int tid = threadIdx.x;
  const int wave = tid >> 6, lane = tid & 63, l16 = lane & 15, quad = lane >> 4;
  const int wm = wave >> 2, wn = wave & 3;
  const int nbase = blockIdx.x * 128, mbase = blockIdx.y * 128;
  const int srow = wave * 16 + (lane >> 3);
  const int sc = lane & 7;

  auto stage = [&](int kk, int nbuf) {
#pragma unroll
    for (int i = 0; i < 2; ++i) {
      const int row = srow + i * 8;
      const int c = sc ^ (row & 7);
      gl_lds16(A + (size_t)(mbase + row) * HID + kk + c * 8,
               &Al[nbuf][(wave * 16 + i * 8) * 64]);
      gl_lds16(Wh + (size_t)(nbase + row) * HID + kk + c * 8,
               &Bl[nbuf][(wave * 16 + i * 8) * 64]);
    }
  };

  const f32x4 z4 = {0.f, 0.f, 0.f, 0.f};
  f32x4 acc[4][2];
#pragma unroll
  for (int mt = 0; mt < 4; ++mt)
#pragma unroll
    for (int nt = 0; nt < 2; ++nt) acc[mt][nt] = z4;

  stage(0, 0);
  for (int t = 0; t < HID / 64; ++t) {
    const int buf = t & 1;
    __syncthreads();
    if (t + 1 < HID / 64) stage((t + 1) * 64, buf ^ 1);
    const int sw = l16 & 7;
    f16x8 b0[2], b1[2];
#pragma unroll
    for (int nt = 0; nt < 2; ++nt) {
      const int brow = wn * 32 + nt * 16 + l16;
      b0[nt] = ld8(&Bl[buf][brow * 64 + (quad ^ sw) * 8]);
      b1[nt] = ld8(&Bl[buf][brow * 64 + ((quad + 4) ^ sw) * 8]);
    }
#pragma unroll
    for (int mt = 0; mt < 4; ++mt) {
      const int arow = wm * 64 + mt * 16 + l16;
      const f16x8 a0 = ld8(&Al[buf][arow * 64 + (quad ^ sw) * 8]);
      const f16x8 a1 = ld8(&Al[buf][arow * 64 + ((quad + 4) ^ sw) * 8]);
#pragma unroll
      for (int nt = 0; nt < 2; ++nt) {
        acc[mt][nt] = MFMA(a0, b0[nt], acc[mt][nt]);
        acc[mt][nt] = MFMA(a1, b1[nt], acc[mt][nt]);
      }
    }
  }
#pragma unroll
  for (int nt = 0; nt < 2; ++nt) {
    const int col = nbase + wn * 32 + nt * 16 + l16;
    const float bv = bias[col];
#pragma unroll
    for (int mt = 0; mt < 4; ++mt) {
#pragma unroll
      for (int r = 0; r < 4; ++r) {
        const int row = mbase + wm * 64 + mt * 16 + quad * 4 + r;
        const float v = acc[mt][nt][r] + bv;
        const float g = 0.5f * v * (1.f + erff(v * 0.70710678118654752f));
        Xout[(size_t)row * HID + col] = g + resid[(size_t)row * HID + col];
      }
    }
  }
}

// ---------------------------------------------------------------------------
// LayerNorm over HID=1024 per token row.
// ---------------------------------------------------------------------------
__global__ __launch_bounds__(256) void ln_kernel(const float* __restrict__ X,
                                                 const float* __restrict__ gamma,
                                                 const float* __restrict__ beta,
                                                 float* __restrict__ out) {
  const int row = blockIdx.x, tid = threadIdx.x;
  const int lane = tid & 63, wave = tid >> 6;
  const float4 v = *(const float4*)(X + (size_t)row * HID + tid * 4);
  float s1 = v.x + v.y + v.z + v.w;
  float s2 = v.x * v.x + v.y * v.y + v.z * v.z + v.w * v.w;
#pragma unroll
  for (int off = 1; off < 64; off <<= 1) {
    s1 += __shfl_xor(s1, off);
    s2 += __shfl_xor(s2, off);
  }
  __shared__ float r1[4], r2[4];
  if (lane == 0) { r1[wave] = s1; r2[wave] = s2; }
  __syncthreads();
  s1 = r1[0] + r1[1] + r1[2] + r1[3];
  s2 = r2[0] + r2[1] + r2[2] + r2[3];
  const float mu = s1 * (1.f / HID);
  const float var = s2 * (1.f / HID) - mu * mu;
  const float rstd = rsqrtf(var + 1e-5f);
  const float4 g = *(const float4*)(gamma + tid * 4);
  const float4 be = *(const float4*)(beta + tid * 4);
  float4 ov;
  ov.x = (v.x - mu) * rstd * g.x + be.x;
  ov.y = (v.y - mu) * rstd * g.y + be.y;
  ov.z = (v.z - mu) * rstd * g.z + be.z;
  ov.w = (v.w - mu) * rstd * g.w + be.w;
  *(float4*)(out + (size_t)row * HID + tid * 4) = ov;
}

// ---------------------------------------------------------------------------
// Workspace:
//   ctx fp16 [ 0, 8M)
//   Xb  fp32 [ 8M,24M)
//   Wh  fp16 [24M,26M)
// ---------------------------------------------------------------------------
extern "C" void kernel_launch(void* const* d_in, const int* in_sizes, int n_in,
                              void* d_out, int out_size, void* d_ws, size_t ws_size,
                              hipStream_t stream) {
  (void)in_sizes; (void)n_in; (void)out_size; (void)ws_size;
  const float* input_embed = (const float*)d_in[0];
  const float* kg_embed    = (const float*)d_in[1];
  // d_in[2] = input_mask: additive per-query constant -> softmax-invariant, unused
  const float* kg_mask = (const float*)d_in[3];
  const float* Wq    = (const float*)d_in[4];
  const float* Wk    = (const float*)d_in[5];
  const float* Wv    = (const float*)d_in[6];
  const float* W_lin = (const float*)d_in[7];
  const float* b_lin = (const float*)d_in[8];
  const float* gamma = (const float*)d_in[9];
  const float* beta  = (const float*)d_in[10];

  char* ws = (char*)d_ws;
  _Float16* ctx = (_Float16*)(ws);
  float*    Xb  = (float*)(ws + (8u << 20));
  _Float16* Wh  = (_Float16*)(ws + (24u << 20));

  attn_kernel<<<dim3(128, 2), dim3(512), 0, stream>>>(input_embed, kg_embed, Wq, Wk, Wv,
                                                      kg_mask, ctx);
  wconv_kernel<<<dim3(1024), dim3(256), 0, stream>>>(W_lin, Wh);
  linear_kernel<<<dim3(8, 32), dim3(512), 0, stream>>>(ctx, Wh, b_lin, input_embed, Xb);
  ln_kernel<<<dim3(NTOK), dim3(256), 0, stream>>>(Xb, gamma, beta, (float*)d_out);
}